// Round 3
// baseline (11333.950 us; speedup 1.0000x reference)
//
#include <hip/hip_runtime.h>
#include <cstdint>
#include <cfloat>
#include <cmath>

// ---------------------------------------------------------------------------
// MossTTS local transformer decode. B=256,H=1024,L=4,I=4096,V=1027,C=16.
// seq_len==1 -> attention == repeat(v); w_q/w_k/q_norm/k_norm dead.
// Round 3: fp32-faithful GEMMs on the f16 MFMA pipe via 2-way operand split
// (x = hi + lo*2^-11, both f16; C = S(AhBh) + [S(AhBl)+S(AlBh)]*2^-11; the
// dropped AlBl term is ~2^-22 relative — same order as fp32 reorder noise).
// Weights pre-split + pre-transposed to [N][K] f16 hi/lo once per launch;
// activations pre-split by the preceding fused reduce/norm kernel. GEMM has
// no LDS/barriers: frags load straight from L2.
// ws tiers: A >=330MB full MFMA; B >=258MB MFMA body + fp32 logits;
// C >=22.6MB round-2 fp32; D small round-2 fp32.
// ---------------------------------------------------------------------------

namespace {
constexpr int B = 256, H = 1024, L = 4;
constexpr int I = 4096, V = 1027, C = 16;
constexpr int KV = 512;
constexpr int VP = 1088;  // V padded to 17*64 for MFMA logits
}

typedef _Float16 half8_t __attribute__((ext_vector_type(8)));
typedef _Float16 half4_t __attribute__((ext_vector_type(4)));
typedef float f4_t __attribute__((ext_vector_type(4)));

// ------------------------------ threefry2x32 -------------------------------
__device__ __forceinline__ void tf2x32(uint32_t k0, uint32_t k1,
                                       uint32_t x0, uint32_t x1,
                                       uint32_t& o0, uint32_t& o1) {
  uint32_t k2 = k0 ^ k1 ^ 0x1BD11BDAu;
  x0 += k0; x1 += k1;
#define TFR(r) { x0 += x1; x1 = (x1 << r) | (x1 >> (32 - r)); x1 ^= x0; }
  TFR(13) TFR(15) TFR(26) TFR(6)
  x0 += k1; x1 += k2 + 1u;
  TFR(17) TFR(29) TFR(16) TFR(24)
  x0 += k2; x1 += k0 + 2u;
  TFR(13) TFR(15) TFR(26) TFR(6)
  x0 += k0; x1 += k1 + 3u;
  TFR(17) TFR(29) TFR(16) TFR(24)
  x0 += k1; x1 += k2 + 4u;
  TFR(13) TFR(15) TFR(26) TFR(6)
  x0 += k2; x1 += k0 + 5u;
#undef TFR
  o0 = x0; o1 = x1;
}

__device__ __forceinline__ float gumbel_for(uint32_t k0, uint32_t k1,
                                            uint32_t idx) {
  uint32_t o0, o1;
  tf2x32(k0, k1, 0u, idx, o0, o1);
  uint32_t bits = o0 ^ o1;
  float f = __uint_as_float((bits >> 9) | 0x3f800000u) - 1.0f;
  float u = fmaxf(FLT_MIN, f + FLT_MIN);
  return -logf(-logf(u));
}

// ------------------------------ f16 split ----------------------------------
__device__ __forceinline__ void split1(float x, _Float16& hi, _Float16& lo) {
  _Float16 h = (_Float16)x;
  float d = x - (float)h;        // exact
  hi = h;
  lo = (_Float16)(d * 2048.0f);  // lo carries bits 12..22
}

// =================== weight pre-split kernels (once/launch) =================
// input W [Kin][Nin] fp32 -> output [Nin][Kout] f16 hi/lo (transposed).
// FOLD: Kout=512 logical rows kk -> W rows k1=((kk>>6)<<7)+(kk&63), k1+64 added
// (repeat-KV gather folded into Wo). grid: (Nin/32, Kout/32, nmat)
template <bool FOLD>
__global__ __launch_bounds__(256) void split_t_k(
    const float* __restrict__ W, _Float16* __restrict__ Wh,
    _Float16* __restrict__ Wl, int Kout, int Nin,
    size_t in_stride, size_t out_stride) {
  __shared__ float ts[32][33];
  const float* w = W + blockIdx.z * in_stride;
  _Float16* oh = Wh + blockIdx.z * out_stride;
  _Float16* ol = Wl + blockIdx.z * out_stride;
  const int n0 = blockIdx.x * 32, k0 = blockIdx.y * 32;
  const int tid = threadIdx.x;
  {
    int r = tid >> 3, c4 = (tid & 7) * 4;
    int kk = k0 + r;
    float4 v;
    if (FOLD) {
      int k1 = ((kk >> 6) << 7) + (kk & 63);
      float4 a = *(const float4*)&w[(size_t)k1 * Nin + n0 + c4];
      float4 b = *(const float4*)&w[(size_t)(k1 + 64) * Nin + n0 + c4];
      v = float4{a.x + b.x, a.y + b.y, a.z + b.z, a.w + b.w};
    } else {
      v = *(const float4*)&w[(size_t)kk * Nin + n0 + c4];
    }
    ts[r][c4 + 0] = v.x; ts[r][c4 + 1] = v.y;
    ts[r][c4 + 2] = v.z; ts[r][c4 + 3] = v.w;
  }
  __syncthreads();
  {
    int n = tid >> 3, kc = (tid & 7) * 4;
    half4_t hh, ll;
#pragma unroll
    for (int j = 0; j < 4; ++j) {
      _Float16 a, b;
      split1(ts[kc + j][n], a, b);
      hh[j] = a; ll[j] = b;
    }
    size_t off = (size_t)(n0 + n) * Kout + k0 + kc;
    *(half4_t*)&oh[off] = hh;
    *(half4_t*)&ol[off] = ll;
  }
}

// lm_heads [C][V][H] fp32 -> [C][VP][H] f16 hi/lo (no transpose; pad rows 0)
__global__ __launch_bounds__(256) void split_lm_k(
    const float* __restrict__ lm, _Float16* __restrict__ Lh,
    _Float16* __restrict__ Ll) {
  size_t flat = ((size_t)blockIdx.x * 256 + threadIdx.x) * 4;
  if (flat >= (size_t)C * VP * H) return;
  int i = (int)(flat / ((size_t)VP * H));
  size_t rem = flat - (size_t)i * VP * H;
  int n = (int)(rem / H);
  int k = (int)(rem - (size_t)n * H);
  float4 v = {0.f, 0.f, 0.f, 0.f};
  if (n < V) v = *(const float4*)&lm[(size_t)i * V * H + (size_t)n * H + k];
  half4_t hh, ll;
  float xs[4] = {v.x, v.y, v.z, v.w};
#pragma unroll
  for (int j = 0; j < 4; ++j) { _Float16 a, b; split1(xs[j], a, b); hh[j] = a; ll[j] = b; }
  *(half4_t*)&Lh[flat] = hh;
  *(half4_t*)&Ll[flat] = ll;
}

// ===================== fused norm / reduce / split kernels ==================
// h=src; r=rsqrt(mean h^2+eps); if xh: (xh,xl)=split(h*r*wn). block/row.
__global__ __launch_bounds__(256) void copy_rms_split_k(
    const float* __restrict__ src, float* __restrict__ h, float* __restrict__ r,
    const float* __restrict__ wn, _Float16* __restrict__ xh,
    _Float16* __restrict__ xl) {
  int b = blockIdx.x, tid = threadIdx.x;
  float4 v = *(const float4*)&src[(size_t)b * H + tid * 4];
  *(float4*)&h[(size_t)b * H + tid * 4] = v;
  float s = v.x * v.x + v.y * v.y + v.z * v.z + v.w * v.w;
  for (int o = 32; o > 0; o >>= 1) s += __shfl_down(s, o, 64);
  __shared__ float red[4];
  __shared__ float sr;
  if ((tid & 63) == 0) red[tid >> 6] = s;
  __syncthreads();
  if (tid == 0) {
    float t = red[0] + red[1] + red[2] + red[3];
    sr = 1.0f / sqrtf(t * (1.0f / 1024.0f) + 1e-6f);
    r[b] = sr;
  }
  __syncthreads();
  if (xh) {
    float rr = sr;
    float4 w = *(const float4*)&wn[tid * 4];
    float xs[4] = {v.x * rr * w.x, v.y * rr * w.y, v.z * rr * w.z, v.w * rr * w.w};
    half4_t hh, ll;
#pragma unroll
    for (int j = 0; j < 4; ++j) { _Float16 a, c; split1(xs[j], a, c); hh[j] = a; ll[j] = c; }
    *(half4_t*)&xh[(size_t)b * H + tid * 4] = hh;
    *(half4_t*)&xl[(size_t)b * H + tid * 4] = ll;
  }
}

// v = sum split-K partials -> f16 split (flat over 256*512)
__global__ __launch_bounds__(256) void red_v_split_k(
    const float* __restrict__ part, int S,
    _Float16* __restrict__ vh, _Float16* __restrict__ vl) {
  int i4 = (blockIdx.x * 256 + threadIdx.x) * 4;
  float4 s = {0.f, 0.f, 0.f, 0.f};
  for (int ss = 0; ss < S; ++ss) {
    float4 p = *(const float4*)&part[(size_t)ss * (256 * KV) + i4];
    s.x += p.x; s.y += p.y; s.z += p.z; s.w += p.w;
  }
  half4_t hh, ll;
  float xs[4] = {s.x, s.y, s.z, s.w};
#pragma unroll
  for (int j = 0; j < 4; ++j) { _Float16 a, b; split1(xs[j], a, b); hh[j] = a; ll[j] = b; }
  *(half4_t*)&vh[i4] = hh;
  *(half4_t*)&vl[i4] = ll;
}

// h += sum partials; r=rms; (xh,xl)=split(h*r*wn). block/row, N=1024.
__global__ __launch_bounds__(256) void red_add_rms_split_k(
    const float* __restrict__ part, int S, float* __restrict__ h,
    float* __restrict__ r, const float* __restrict__ wn,
    _Float16* __restrict__ xh, _Float16* __restrict__ xl) {
  int b = blockIdx.x, tid = threadIdx.x;
  size_t off = (size_t)b * H + tid * 4;
  float4 a = *(const float4*)&h[off];
  for (int ss = 0; ss < S; ++ss) {
    float4 p = *(const float4*)&part[(size_t)ss * (256 * H) + off];
    a.x += p.x; a.y += p.y; a.z += p.z; a.w += p.w;
  }
  *(float4*)&h[off] = a;
  float s = a.x * a.x + a.y * a.y + a.z * a.z + a.w * a.w;
  for (int o = 32; o > 0; o >>= 1) s += __shfl_down(s, o, 64);
  __shared__ float red[4];
  __shared__ float sr;
  if ((tid & 63) == 0) red[tid >> 6] = s;
  __syncthreads();
  if (tid == 0) {
    float t = red[0] + red[1] + red[2] + red[3];
    sr = 1.0f / sqrtf(t * (1.0f / 1024.0f) + 1e-6f);
    r[b] = sr;
  }
  __syncthreads();
  if (xh) {
    float rr = sr;
    float4 w = *(const float4*)&wn[tid * 4];
    float xs[4] = {a.x * rr * w.x, a.y * rr * w.y, a.z * rr * w.z, a.w * rr * w.w};
    half4_t hh, ll;
#pragma unroll
    for (int j = 0; j < 4; ++j) { _Float16 p, q; split1(xs[j], p, q); hh[j] = p; ll[j] = q; }
    *(half4_t*)&xh[off] = hh;
    *(half4_t*)&xl[off] = ll;
  }
}

// m = silu(sum Pg) * (sum Pu) -> f16 split (flat over 256*4096)
__global__ __launch_bounds__(256) void red_gu_split_k(
    const float* __restrict__ Pg, const float* __restrict__ Pu, int S,
    _Float16* __restrict__ mh, _Float16* __restrict__ ml) {
  int i4 = (blockIdx.x * 256 + threadIdx.x) * 4;
  float4 g = {0.f, 0.f, 0.f, 0.f}, u = {0.f, 0.f, 0.f, 0.f};
  for (int ss = 0; ss < S; ++ss) {
    float4 pg = *(const float4*)&Pg[(size_t)ss * (256 * I) + i4];
    float4 pu = *(const float4*)&Pu[(size_t)ss * (256 * I) + i4];
    g.x += pg.x; g.y += pg.y; g.z += pg.z; g.w += pg.w;
    u.x += pu.x; u.y += pu.y; u.z += pu.z; u.w += pu.w;
  }
  float gs[4] = {g.x, g.y, g.z, g.w};
  float us[4] = {u.x, u.y, u.z, u.w};
  half4_t hh, ll;
#pragma unroll
  for (int j = 0; j < 4; ++j) {
    float sg = 1.0f / (1.0f + expf(-gs[j]));
    float m = gs[j] * sg * us[j];
    _Float16 a, b; split1(m, a, b); hh[j] = a; ll[j] = b;
  }
  *(half4_t*)&mh[i4] = hh;
  *(half4_t*)&ml[i4] = ll;
}

// ============================ MFMA split-GEMM ==============================
// C[256][N] partial = A[256][K] * B^T  (B stored [N][K] f16 hi/lo).
// Wave computes 32x32 via 2x2 mfma_f32_16x16x32_f16 C-tiles; block = 64-col
// strip x 2 M-tiles (rows blockIdx.y*128..+127); grid (nb[*2], 2, S).
// TWO_B: second half of grid.x uses (B2h,B2l)->P2 (fused gate/up launch).
// Verified layouts (learn_hip m120/m89): A[m=lane&15][k=quad*8+j],
// B[k][n] from Bt[n][k] rows, C/D col=lane&15 row=quad*4+reg.
template <bool TWO_B>
__global__ __launch_bounds__(256) void mgemm_k(
    const _Float16* __restrict__ Ah, const _Float16* __restrict__ Al,
    const _Float16* __restrict__ Bh0, const _Float16* __restrict__ Bl0,
    const _Float16* __restrict__ B2h, const _Float16* __restrict__ B2l,
    float* __restrict__ P0, float* __restrict__ P2,
    int K, int Kslice, int ldp, int nb) {
  int bx = blockIdx.x;
  const _Float16* Bh = Bh0;
  const _Float16* Bl = Bl0;
  float* out = P0;
  if (TWO_B && bx >= nb) { bx -= nb; Bh = B2h; Bl = B2l; out = P2; }
  const int tid = threadIdx.x, lane = tid & 63, wv = tid >> 6;
  const int wm = (wv & 1) * 32, wn = (wv >> 1) * 32;
  const int l15 = lane & 15, quad = lane >> 4;
  const int mrow = blockIdx.y * 128 + wm + l15;
  const int nrow = bx * 64 + wn + l15;
  const int ks0 = blockIdx.z * Kslice;
  f4_t c1[2][2][2] = {};
  f4_t c2[2][2][2] = {};
  for (int k0 = ks0; k0 < ks0 + Kslice; k0 += 32) {
    const int kq = k0 + quad * 8;
    half8_t bh[2], bl[2];
#pragma unroll
    for (int g = 0; g < 2; ++g) {
      size_t ro = (size_t)(nrow + g * 16) * K + kq;
      bh[g] = *(const half8_t*)&Bh[ro];
      bl[g] = *(const half8_t*)&Bl[ro];
    }
#pragma unroll
    for (int mt = 0; mt < 2; ++mt) {
      half8_t ah[2], al[2];
#pragma unroll
      for (int g = 0; g < 2; ++g) {
        size_t ro = (size_t)(mrow + mt * 64 + g * 16) * K + kq;
        ah[g] = *(const half8_t*)&Ah[ro];
        al[g] = *(const half8_t*)&Al[ro];
      }
#pragma unroll
      for (int gi = 0; gi < 2; ++gi)
#pragma unroll
        for (int gj = 0; gj < 2; ++gj) {
          c1[mt][gi][gj] = __builtin_amdgcn_mfma_f32_16x16x32_f16(
              ah[gi], bh[gj], c1[mt][gi][gj], 0, 0, 0);
          c2[mt][gi][gj] = __builtin_amdgcn_mfma_f32_16x16x32_f16(
              ah[gi], bl[gj], c2[mt][gi][gj], 0, 0, 0);
          c2[mt][gi][gj] = __builtin_amdgcn_mfma_f32_16x16x32_f16(
              al[gi], bh[gj], c2[mt][gi][gj], 0, 0, 0);
        }
    }
  }
  float* base = out + (size_t)blockIdx.z * 256 * ldp;
#pragma unroll
  for (int mt = 0; mt < 2; ++mt)
#pragma unroll
    for (int gi = 0; gi < 2; ++gi)
#pragma unroll
      for (int gj = 0; gj < 2; ++gj)
#pragma unroll
        for (int i = 0; i < 4; ++i) {
          int row = blockIdx.y * 128 + mt * 64 + wm + gi * 16 + quad * 4 + i;
          int col = bx * 64 + wn + gj * 16 + l15;
          base[(size_t)row * ldp + col] =
              c1[mt][gi][gj][i] + c2[mt][gi][gj][i] * (1.0f / 2048.0f);
        }
}

// ===================== fp32 fallback kernels (round-2) ======================
__global__ __launch_bounds__(256) void fold_k(const float* __restrict__ wo,
                                              float* __restrict__ wof) {
  int blk = blockIdx.x;
  int l = blk >> 9, c = blk & 511;
  int kb = c >> 6, jl = c & 63;
  const float* w = wo + (size_t)l * H * H;
  int k1 = kb * 128 + jl, k2 = k1 + 64;
  int j = threadIdx.x * 4;
  float4 a = *(const float4*)&w[(size_t)k1 * H + j];
  float4 bq = *(const float4*)&w[(size_t)k2 * H + j];
  float4 o = {a.x + bq.x, a.y + bq.y, a.z + bq.z, a.w + bq.w};
  *(float4*)&wof[((size_t)l * KV + c) * H + j] = o;
}

template <bool NORM, bool GATHER, bool BT, bool BOUND>
__global__ __launch_bounds__(256) void gemm64_k(
    const float* __restrict__ A, int lda,
    const float* __restrict__ rv, const float* __restrict__ wn,
    const float* __restrict__ Bm, int ldb,
    float* __restrict__ Cp, int N, int Kslice) {
  __shared__ __align__(16) float As[32][68];
  __shared__ __align__(16) float Bs[32][68];
  const int tid = threadIdx.x;
  const int tx = tid & 15, ty = tid >> 4;
  const int bm = blockIdx.y * 64;
  const int bn = blockIdx.x * 64;
  const int ks0 = blockIdx.z * Kslice;
  float4 acc[4];
#pragma unroll
  for (int i = 0; i < 4; ++i) acc[i] = float4{0.f, 0.f, 0.f, 0.f};

  for (int k0 = 0; k0 < Kslice; k0 += 32) {
    const int kbase = ks0 + k0;
#pragma unroll
    for (int s = 0; s < 2; ++s) {
      int slot = tid + s * 256;
      int rI = slot >> 3, c = slot & 7;
      int k = kbase + c * 4;
      int col = GATHER ? (((k >> 7) << 6) | (k & 63)) : k;
      float4 av = *(const float4*)&A[(size_t)(bm + rI) * lda + col];
      if (NORM) {
        float sc = rv[bm + rI];
        float4 wv = *(const float4*)&wn[k];
        av.x *= sc * wv.x; av.y *= sc * wv.y;
        av.z *= sc * wv.z; av.w *= sc * wv.w;
      }
      As[c * 4 + 0][rI] = av.x; As[c * 4 + 1][rI] = av.y;
      As[c * 4 + 2][rI] = av.z; As[c * 4 + 3][rI] = av.w;
    }
#pragma unroll
    for (int s = 0; s < 2; ++s) {
      int slot = tid + s * 256;
      if (!BT) {
        int kI = slot >> 4, c4 = slot & 15;
        float4 bv = *(const float4*)&Bm[(size_t)(kbase + kI) * ldb + bn + c4 * 4];
        *(float4*)&Bs[kI][c4 * 4] = bv;
      } else {
        int nI = slot >> 3, c = slot & 7;
        int n = bn + nI;
        float4 bv = {0.f, 0.f, 0.f, 0.f};
        if (!BOUND || n < N)
          bv = *(const float4*)&Bm[(size_t)n * ldb + kbase + c * 4];
        Bs[c * 4 + 0][nI] = bv.x; Bs[c * 4 + 1][nI] = bv.y;
        Bs[c * 4 + 2][nI] = bv.z; Bs[c * 4 + 3][nI] = bv.w;
      }
    }
    __syncthreads();
#pragma unroll
    for (int kk = 0; kk < 32; ++kk) {
      float4 a = *(const float4*)&As[kk][ty * 4];
      float4 b = *(const float4*)&Bs[kk][tx * 4];
      float ar[4] = {a.x, a.y, a.z, a.w};
#pragma unroll
      for (int i = 0; i < 4; ++i) {
        acc[i].x = fmaf(ar[i], b.x, acc[i].x);
        acc[i].y = fmaf(ar[i], b.y, acc[i].y);
        acc[i].z = fmaf(ar[i], b.z, acc[i].z);
        acc[i].w = fmaf(ar[i], b.w, acc[i].w);
      }
    }
    __syncthreads();
  }
  float* base = Cp + (size_t)blockIdx.z * 256 * N;
#pragma unroll
  for (int i = 0; i < 4; ++i) {
    int row = bm + ty * 4 + i, colb = bn + tx * 4;
    if (!BOUND) {
      *(float4*)&base[(size_t)row * N + colb] = acc[i];
    } else {
      float vals[4] = {acc[i].x, acc[i].y, acc[i].z, acc[i].w};
      for (int j = 0; j < 4; ++j)
        if (colb + j < N) base[(size_t)row * N + colb + j] = vals[j];
    }
  }
}

__global__ __launch_bounds__(256) void gemm_gu_k(
    const float* __restrict__ hm, const float* __restrict__ rv,
    const float* __restrict__ wn,
    const float* __restrict__ Bg, const float* __restrict__ Bu,
    float* __restrict__ Mo) {
  __shared__ __align__(16) float As[32][68];
  __shared__ __align__(16) float Gs[32][36];
  __shared__ __align__(16) float Us[32][36];
  const int tid = threadIdx.x;
  const int tx = tid & 15, ty = tid >> 4;
  const int bm = blockIdx.y * 64;
  const int bn = blockIdx.x * 32;
  float2 ag[4], au[4];
#pragma unroll
  for (int i = 0; i < 4; ++i) { ag[i] = float2{0.f, 0.f}; au[i] = float2{0.f, 0.f}; }
  for (int k0 = 0; k0 < H; k0 += 32) {
#pragma unroll
    for (int s = 0; s < 2; ++s) {
      int slot = tid + s * 256;
      int rI = slot >> 3, c = slot & 7;
      int k = k0 + c * 4;
      float4 av = *(const float4*)&hm[(size_t)(bm + rI) * H + k];
      float sc = rv[bm + rI];
      float4 wv = *(const float4*)&wn[k];
      av.x *= sc * wv.x; av.y *= sc * wv.y;
      av.z *= sc * wv.z; av.w *= sc * wv.w;
      As[c * 4 + 0][rI] = av.x; As[c * 4 + 1][rI] = av.y;
      As[c * 4 + 2][rI] = av.z; As[c * 4 + 3][rI] = av.w;
    }
    {
      int kI = tid >> 3, c4 = tid & 7;
      float4 gv = *(const float4*)&Bg[(size_t)(k0 + kI) * I + bn + c4 * 4];
      float4 uv = *(const float4*)&Bu[(size_t)(k0 + kI) * I + bn + c4 * 4];
      *(float4*)&Gs[kI][c4 * 4] = gv;
      *(float4*)&Us[kI][c4 * 4] = uv;
    }
    __syncthreads();
#pragma unroll
    for (int kk = 0; kk < 32; ++kk) {
      float4 a = *(const float4*)&As[kk][ty * 4];
      float2 g = *(const float2*)&Gs[kk][tx * 2];
      float2 u = *(const float2*)&Us[kk][tx * 2];
      float ar[4] = {a.x, a.y, a.z, a.w};
#pragma unroll
      for (int i = 0; i < 4; ++i) {
        ag[i].x = fmaf(ar[i], g.x, ag[i].x);
        ag[i].y = fmaf(ar[i], g.y, ag[i].y);
        au[i].x = fmaf(ar[i], u.x, au[i].x);
        au[i].y = fmaf(ar[i], u.y, au[i].y);
      }
    }
    __syncthreads();
  }
#pragma unroll
  for (int i = 0; i < 4; ++i) {
    int row = bm + ty * 4 + i, col = bn + tx * 2;
    float g0 = ag[i].x, g1 = ag[i].y;
    float s0 = 1.0f / (1.0f + expf(-g0));
    float s1 = 1.0f / (1.0f + expf(-g1));
    float2 o = {g0 * s0 * au[i].x, g1 * s1 * au[i].y};
    *(float2*)&Mo[(size_t)row * I + col] = o;
  }
}

__global__ __launch_bounds__(256) void red_v_k(const float* __restrict__ part,
                                               float* __restrict__ v, int S) {
  int i4 = (blockIdx.x * 256 + threadIdx.x) * 4;
  float4 s = {0.f, 0.f, 0.f, 0.f};
  for (int ss = 0; ss < S; ++ss) {
    float4 p = *(const float4*)&part[(size_t)ss * (256 * KV) + i4];
    s.x += p.x; s.y += p.y; s.z += p.z; s.w += p.w;
  }
  *(float4*)&v[i4] = s;
}

__global__ __launch_bounds__(256) void red_add_rms_k(const float* __restrict__ part,
                                                     float* __restrict__ h,
                                                     float* __restrict__ r, int S) {
  int b = blockIdx.x, tid = threadIdx.x;
  size_t off = (size_t)b * H + tid * 4;
  float4 a = *(const float4*)&h[off];
  for (int ss = 0; ss < S; ++ss) {
    float4 p = *(const float4*)&part[(size_t)ss * (256 * H) + off];
    a.x += p.x; a.y += p.y; a.z += p.z; a.w += p.w;
  }
  *(float4*)&h[off] = a;
  float s = a.x * a.x + a.y * a.y + a.z * a.z + a.w * a.w;
  for (int o = 32; o > 0; o >>= 1) s += __shfl_down(s, o, 64);
  __shared__ float red[4];
  if ((tid & 63) == 0) red[tid >> 6] = s;
  __syncthreads();
  if (tid == 0) {
    float t = red[0] + red[1] + red[2] + red[3];
    r[b] = 1.0f / sqrtf(t * (1.0f / 1024.0f) + 1e-6f);
  }
}

// ============ head: reduce + reppen + sample + embed + next-x ==============
__global__ __launch_bounds__(256) void head_k(
    const float* __restrict__ part, int S, int ldp,
    const int* __restrict__ gh, const int* __restrict__ gen_step_p,
    int step, const float* __restrict__ embed_next,
    float* __restrict__ h, float* __restrict__ r,
    const float* __restrict__ win0, _Float16* __restrict__ xh,
    _Float16* __restrict__ xl, int* __restrict__ out) {
  constexpr int TOPK = 30;
  constexpr int KMAX = 64;
  const int b = blockIdx.x, tid = threadIdx.x;
  __shared__ float sl[V];
  __shared__ float rv_[256]; __shared__ int ri[256];
  __shared__ float topv[TOPK]; __shared__ int topi[TOPK];
  __shared__ float kv[KMAX]; __shared__ int ki[KMAX]; __shared__ int keepf[KMAX];
  __shared__ uint32_t skey[2];
  __shared__ int scnt, sn, stok;
  __shared__ float redf[4];
  __shared__ float srr;

  if (tid == 0) {
    uint32_t o0, o1;
    tf2x32(0u, 1234u, 0u, (uint32_t)step, o0, o1);
    skey[0] = o0; skey[1] = o1;
    scnt = 0;
  }
  for (int v = tid; v < V; v += 256) {
    float s = 0.f;
    for (int ss = 0; ss < S; ++ss)
      s += part[(size_t)ss * 256 * ldp + (size_t)b * ldp + v];
    sl[v] = s;
  }
  __syncthreads();
  int gs = *gen_step_p;
  int cnt = gs < 50 ? gs : 50;
  int start = gs - cnt;
  int tkn = -1; float val = 0.f;
  if (tid < cnt) {
    tkn = gh[(size_t)b * 200 * C + (size_t)(start + tid) * C + step];
    val = sl[tkn];
  }
  __syncthreads();
  if (tid < cnt) sl[tkn] = (val < 0.f) ? val * 1.1f : val / 1.1f;
  __syncthreads();
  for (int v = tid; v < V; v += 256) sl[v] = sl[v] / 0.8f;
  __syncthreads();

  for (int it = 0; it < TOPK; ++it) {
    float bv = -INFINITY; int bi = 0x7fffffff;
    for (int v = tid; v < V; v += 256) {
      float x = sl[v];
      if (x > bv) { bv = x; bi = v; }
    }
    rv_[tid] = bv; ri[tid] = bi;
    __syncthreads();
    for (int s = 128; s > 0; s >>= 1) {
      if (tid < s) {
        float ov = rv_[tid + s]; int oi = ri[tid + s];
        if (ov > rv_[tid] || (ov == rv_[tid] && oi < ri[tid])) { rv_[tid] = ov; ri[tid] = oi; }
      }
      __syncthreads();
    }
    if (tid == 0) { topv[it] = rv_[0]; topi[it] = ri[0]; sl[ri[0]] = -INFINITY; }
    __syncthreads();
  }
  if (tid < TOPK) sl[topi[tid]] = topv[tid];
  __syncthreads();
  const float thr = topv[TOPK - 1];
  for (int v = tid; v < V; v += 256) {
    if (sl[v] >= thr) {
      int p = atomicAdd(&scnt, 1);
      if (p < KMAX) { kv[p] = sl[v]; ki[p] = v; }
    }
  }
  __syncthreads();

  if (tid == 0) {
    int n = scnt < KMAX ? scnt : KMAX;
    for (int a = 1; a < n; ++a) {
      float cv = kv[a]; int ci = ki[a];
      int p = a - 1;
      while (p >= 0 && (kv[p] > cv || (kv[p] == cv && ki[p] > ci))) {
        kv[p + 1] = kv[p]; ki[p + 1] = ki[p]; --p;
      }
      kv[p + 1] = cv; ki[p + 1] = ci;
    }
    float mx = kv[n - 1];
    float denom = 0.f;
    for (int j = 0; j < n; ++j) denom += expf(kv[j] - mx);
    float c = 0.f;
    for (int j = 0; j < n; ++j) {
      float p = expf(kv[j] - mx) / denom;
      c += p;
      keepf[j] = ((double)c > 0.4) ? 1 : 0;
    }
    sn = n;
  }
  __syncthreads();

  int n = sn;
  rv_[tid] = -INFINITY; ri[tid] = 0x7fffffff;
  if (tid < n && keepf[tid]) {
    uint32_t idx = (uint32_t)b * (uint32_t)V + (uint32_t)ki[tid];
    float g = gumbel_for(skey[0], skey[1], idx);
    rv_[tid] = kv[tid] + g;
    ri[tid] = ki[tid];
  }
  __syncthreads();
  for (int s = 128; s > 0; s >>= 1) {
    if (tid < s) {
      float ov = rv_[tid + s]; int oi = ri[tid + s];
      if (ov > rv_[tid] || (ov == rv_[tid] && oi < ri[tid])) { rv_[tid] = ov; ri[tid] = oi; }
    }
    __syncthreads();
  }
  if (tid == 0) {
    stok = ri[0];
    out[(size_t)b * C + step] = ri[0];
  }
  __syncthreads();

  if (embed_next != nullptr) {
    int tok = stok;
    float4 e = *(const float4*)&embed_next[(size_t)tok * H + tid * 4];
    *(float4*)&h[(size_t)b * H + tid * 4] = e;
    float s = e.x * e.x + e.y * e.y + e.z * e.z + e.w * e.w;
    for (int o = 32; o > 0; o >>= 1) s += __shfl_down(s, o, 64);
    if ((tid & 63) == 0) redf[tid >> 6] = s;
    __syncthreads();
    if (tid == 0) {
      float t = redf[0] + redf[1] + redf[2] + redf[3];
      srr = 1.0f / sqrtf(t * (1.0f / 1024.0f) + 1e-6f);
      r[b] = srr;
    }
    __syncthreads();
    if (xh) {
      float rr = srr;
      float4 w = *(const float4*)&win0[tid * 4];
      float xs[4] = {e.x * rr * w.x, e.y * rr * w.y, e.z * rr * w.z, e.w * rr * w.w};
      half4_t hh, ll;
#pragma unroll
      for (int j = 0; j < 4; ++j) { _Float16 p, q; split1(xs[j], p, q); hh[j] = p; ll[j] = q; }
      *(half4_t*)&xh[(size_t)b * H + tid * 4] = hh;
      *(half4_t*)&xl[(size_t)b * H + tid * 4] = ll;
    }
  }
}

// ------------------------------ launch -------------------------------------
extern "C" void kernel_launch(void* const* d_in, const int* in_sizes, int n_in,
                              void* d_out, int out_size, void* d_ws, size_t ws_size,
                              hipStream_t stream) {
  const float* backbone = (const float*)d_in[0];
  const int*   gh       = (const int*)d_in[1];
  const int*   gen_step = (const int*)d_in[2];
  const float* embed    = (const float*)d_in[3];
  const float* lm       = (const float*)d_in[4];
  const float* w_in     = (const float*)d_in[5];
  const float* w_v      = (const float*)d_in[8];
  const float* w_o      = (const float*)d_in[11];
  const float* w_post   = (const float*)d_in[12];
  const float* w_g      = (const float*)d_in[13];
  const float* w_u      = (const float*)d_in[14];
  const float* w_d      = (const float*)d_in[15];
  const float* fnorm    = (const float*)d_in[16];
  int* out = (int*)d_out;

  const size_t NEED_A = 329253888ull;  // full MFMA incl. f16 lm heads
  const size_t NEED_B = 257950720ull;  // MFMA body, fp32 logits
  int tier = (ws_size >= NEED_A) ? 0 : (ws_size >= NEED_B) ? 1
           : (ws_size >= 22600000ull) ? 2 : 3;

  if (tier <= 1) {
    uint8_t* wsb = (uint8_t*)d_ws;
    float*     h    = (float*)(wsb + 0);             // 1 MB
    float*     r    = (float*)(wsb + 1048576);       // 1 KB
    _Float16*  Asp  = (_Float16*)(wsb + 1049600);    // 4 MB (hi/lo act splits)
    float*     P    = (float*)(wsb + 5243904);       // 17.8 MB partials
    float*     P2   = (float*)(wsb + 23069696);      // 16.8 MB partials (u)
    _Float16*  wvh  = (_Float16*)(wsb + 39846912);
    _Float16*  woh  = (_Float16*)(wsb + 48235520);
    _Float16*  wgh  = (_Float16*)(wsb + 56624128);
    _Float16*  wuh  = (_Float16*)(wsb + 123732992);
    _Float16*  wdh  = (_Float16*)(wsb + 190841856);
    _Float16*  lmh  = (_Float16*)(wsb + 257950720);
    _Float16*  wvl = wvh + (size_t)L * KV * H;
    _Float16*  wol = woh + (size_t)L * H * KV;
    _Float16*  wgl = wgh + (size_t)L * I * H;
    _Float16*  wul = wuh + (size_t)L * I * H;
    _Float16*  wdl = wdh + (size_t)L * H * I;
    _Float16*  lml = lmh + (size_t)C * VP * H;

    // ---- weight pre-split (every launch; ws re-poisoned by harness) ----
    split_t_k<false><<<dim3(KV / 32, H / 32, L), dim3(256), 0, stream>>>(
        w_v, wvh, wvl, H, KV, (size_t)H * KV, (size_t)KV * H);
    split_t_k<true><<<dim3(H / 32, KV / 32, L), dim3(256), 0, stream>>>(
        w_o, woh, wol, KV, H, (size_t)H * H, (size_t)H * KV);
    split_t_k<false><<<dim3(I / 32, H / 32, L), dim3(256), 0, stream>>>(
        w_g, wgh, wgl, H, I, (size_t)H * I, (size_t)I * H);
    split_t_k<false><<<dim3(I / 32, H / 32, L), dim3(256), 0, stream>>>(
        w_u, wuh, wul, H, I, (size_t)H * I, (size_t)I * H);
    split_t_k<false><<<dim3(H / 32, I / 32, L), dim3(256), 0, stream>>>(
        w_d, wdh, wdl, I, H, (size_t)I * H, (size_t)H * I);
    if (tier == 0) {
      int nthr = (C * VP * H) / 4;
      split_lm_k<<<dim3((nthr + 255) / 256), dim3(256), 0, stream>>>(lm, lmh, lml);
    }

    // act split sub-pointers (Asp reused serially: x -> v -> x2 -> m -> x)
    _Float16* xh = Asp;                 _Float16* xl = Asp + 256 * H;
    _Float16* vh = Asp;                 _Float16* vl = Asp + 256 * KV;
    _Float16* mh = Asp;                 _Float16* ml = Asp + 256 * I;

    copy_rms_split_k<<<dim3(256), dim3(256), 0, stream>>>(
        backbone, h, r, w_in, xh, xl);

    constexpr int S1 = 8, S2 = 8, S3 = 4, S4 = 16, S5 = 8;
    for (int i = 0; i < C; ++i) {
      for (int l = 0; l < L; ++l) {
        // G1: v = x @ Wv   [256,1024]x[1024,512]
        mgemm_k<false><<<dim3(8, 2, S1), dim3(256), 0, stream>>>(
            xh, xl, wvh + (size_t)l * KV * H, wvl + (size_t)l * KV * H,
            nullptr, nullptr, P, nullptr, H, H / S1, KV, 8);
        red_v_split_k<<<dim3(128), dim3(256), 0, stream>>>(P, S1, vh, vl);
        // G2: h += v @ Wo' (folded K=512)
        mgemm_k<false><<<dim3(16, 2, S2), dim3(256), 0, stream>>>(
            vh, vl, woh + (size_t)l * H * KV, wol + (size_t)l * H * KV,
            nullptr, nullptr, P, nullptr, KV, KV / S2, H, 16);
        red_add_rms_split_k<<<dim3(256), dim3(256), 0, stream>>>(
            P, S2, h, r, w_post + (size_t)l * H, xh, xl);
        // G3: g and u in one launch (grid.x doubled)
        mgemm_k<true><<<dim3(128, 2, S3), dim3(256), 0, stream>>>(
            xh, xl, wgh + (size_t)l * I * H, wgl + (size_t)l * I * H,
            wuh + (size_t)l * I * H, wul + (size_t)l * I * H,
            P, P2, H, H / S3, I, 64);
        red_gu_split_k<<<dim3(1024), dim3(256), 0, stream>>>(P, P2, S3, mh, ml);
        // G4: h += m @ Wd   [256,4096]x[4096,1024]
        mgemm_k<false><<<dim3(16, 2, S4), dim3(256), 0, stream>>>(
            mh, ml, wdh + (size_t)l * H * I, wdl + (size_t)l * H * I,
            nullptr, nullptr, P, nullptr, I, I / S4, H, 16);
        red_add_rms_split_k<<<dim3(256), dim3(256), 0, stream>>>(
            P, S4, h, r, (l < L - 1) ? w_in + (size_t)(l + 1) * H : fnorm,
            xh, xl);
      }
      int ldp;
      int S5eff;
      if (tier == 0) {
        mgemm_k<false><<<dim3(17, 2, S5), dim3(256), 0, stream>>>(
            xh, xl, lmh + (size_t)i * VP * H, lml + (size_t)i * VP * H,
            nullptr, nullptr, P, nullptr, H, H / S5, VP, 17);
        ldp = VP; S5eff = S5;
      } else {
        gemm64_k<true, false, true, true><<<dim3(17, 4, 8), dim3(256), 0, stream>>>(
            h, H, r, fnorm, lm + (size_t)i * V * H, H, P, V, H / 8);
        ldp = V; S5eff = 8;
      }
      head_k<<<dim3(256), dim3(256), 0, stream>>>(
          P, S5eff, ldp, gh, gen_step, i,
          (i < C - 1) ? embed + (size_t)(i + 1) * V * H : nullptr,
          h, r, w_in, xh, xl, out);
    }
    return;
  }

  // ---------------- fp32 fallback (round-2, proven) ----------------
  float* ws = (float*)d_ws;
  const bool big = (tier == 2);
  float* h    = ws;
  float* v    = ws + 262144;
  float* m    = ws + 393216;
  float* wof  = big ? ws + 1441792 : nullptr;
  float* part = big ? ws + 3538944 : ws + 1441792;
  float* r    = big ? ws + 5642240 : ws + 1966080;

  const int S1 = big ? 16 : 4;
  const int S2 = big ? 8 : 2;
  const int S4 = big ? 8 : 2;
  const int S5 = big ? 8 : 1;

  copy_rms_split_k<<<dim3(256), dim3(256), 0, stream>>>(
      backbone, h, r, nullptr, nullptr, nullptr);
  if (big) fold_k<<<dim3(2048), dim3(256), 0, stream>>>(w_o, wof);

  for (int i = 0; i < C; ++i) {
    for (int l = 0; l < L; ++l) {
      gemm64_k<true, false, false, false><<<dim3(8, 4, S1), dim3(256), 0, stream>>>(
          h, H, r, w_in + (size_t)l * H, w_v + (size_t)l * H * KV, KV,
          part, KV, H / S1);
      red_v_k<<<dim3(128), dim3(256), 0, stream>>>(part, v, S1);
      if (big)
        gemm64_k<false, false, false, false><<<dim3(16, 4, S2), dim3(256), 0, stream>>>(
            v, KV, nullptr, nullptr, wof + (size_t)l * KV * H, H,
            part, H, KV / S2);
      else
        gemm64_k<false, true, false, false><<<dim3(16, 4, S2), dim3(256), 0, stream>>>(
            v, KV, nullptr, nullptr, w_o + (size_t)l * H * H, H,
            part, H, H / S2);
      red_add_rms_k<<<dim3(256), dim3(256), 0, stream>>>(part, h, r, S2);
      gemm_gu_k<<<dim3(128, 4), dim3(256), 0, stream>>>(
          h, r, w_post + (size_t)l * H,
          w_g + (size_t)l * H * I, w_u + (size_t)l * H * I, m);
      gemm64_k<false, false, false, false><<<dim3(16, 4, S4), dim3(256), 0, stream>>>(
          m, I, nullptr, nullptr, w_d + (size_t)l * I * H, H,
          part, H, I / S4);
      red_add_rms_k<<<dim3(256), dim3(256), 0, stream>>>(part, h, r, S4);
    }
    gemm64_k<true, false, true, true><<<dim3(17, 4, S5), dim3(256), 0, stream>>>(
        h, H, r, fnorm, lm + (size_t)i * V * H, H, part, V, H / S5);
    head_k<<<dim3(256), dim3(256), 0, stream>>>(
        part, S5, V, gh, gen_step, i,
        (i < C - 1) ? embed + (size_t)(i + 1) * V * H : nullptr,
        h, r, nullptr, nullptr, nullptr, out);
  }
}